// Round 1
// baseline (322.710 us; speedup 1.0000x reference)
//
#include <hip/hip_runtime.h>

#define KE_CONST 14.3996454784255f

// Kernel 1: per-node precompute.
//   node_data[n] = { Zf, Zf^0.3, covalent_radii[Z], 0 }
// Also zeroes d_out (harness poisons it with 0xAA before every timed launch).
__global__ void zbl_node_prep(const float* __restrict__ node_attrs,
                              const int* __restrict__ atomic_numbers,
                              const float* __restrict__ covalent_radii,
                              float4* __restrict__ node_data,
                              float* __restrict__ out,
                              int n_nodes, int n_elem) {
    int n = blockIdx.x * blockDim.x + threadIdx.x;
    if (n >= n_nodes) return;
    const float* row = node_attrs + (size_t)n * n_elem;
    float best = row[0];
    int bi = 0;
    for (int i = 1; i < n_elem; ++i) {
        float v = row[i];
        if (v > best) { best = v; bi = i; }
    }
    int Z = atomic_numbers[bi];
    float zf = (float)Z;
    float zp = powf(zf, 0.3f);
    float cr = covalent_radii[Z];
    node_data[n] = make_float4(zf, zp, cr, 0.0f);
    out[n] = 0.0f;
}

// Kernel 2: per-edge ZBL pair energy, atomic scatter to receiver.
__global__ void zbl_edge(const float* __restrict__ x,
                         const int* __restrict__ edge_index,
                         const float4* __restrict__ node_data,
                         float* __restrict__ out,
                         int n_edges) {
    int e = blockIdx.x * blockDim.x + threadIdx.x;
    if (e >= n_edges) return;

    int snd = edge_index[e];            // row 0: sender
    int rcv = edge_index[n_edges + e];  // row 1: receiver
    float xv = x[e];

    float4 du = node_data[snd];
    float4 dv = node_data[rcv];

    float rmax = du.z + dv.z;
    if (xv >= rmax) return;  // envelope == 0 -> contribution is exactly 0

    // a = 0.4543 * 0.529 / (Zu^0.3 + Zv^0.3);  t = x / a
    const float inv_a_pref = 1.0f / (0.4543f * 0.529f);
    float t = xv * (du.y + dv.y) * inv_a_pref;

    float phi = 0.1818f  * __expf(-3.2f    * t)
              + 0.5099f  * __expf(-0.9423f * t)
              + 0.2802f  * __expf(-0.4028f * t)
              + 0.02817f * __expf(-0.2016f * t);

    float v = KE_CONST * du.x * dv.x * phi / xv;

    // envelope, p = 6: 1 - 28 r^6 + 48 r^7 - 21 r^8
    float rr = xv / rmax;
    float r2 = rr * rr;
    float r3 = r2 * rr;
    float r6 = r3 * r3;
    float env = 1.0f - 28.0f * r6 + 48.0f * r6 * rr - 21.0f * r6 * r2;

    float val = 0.5f * v * env;
    atomicAdd(&out[rcv], val);
}

extern "C" void kernel_launch(void* const* d_in, const int* in_sizes, int n_in,
                              void* d_out, int out_size, void* d_ws, size_t ws_size,
                              hipStream_t stream) {
    const float* x              = (const float*)d_in[0];
    const float* node_attrs     = (const float*)d_in[1];
    const int*   edge_index     = (const int*)d_in[2];
    const int*   atomic_numbers = (const int*)d_in[3];
    const float* covalent_radii = (const float*)d_in[4];
    float* out = (float*)d_out;

    int n_edges = in_sizes[0];
    int n_elem  = in_sizes[3];
    int n_nodes = in_sizes[1] / n_elem;

    float4* node_data = (float4*)d_ws;  // n_nodes * 16 bytes

    zbl_node_prep<<<(n_nodes + 255) / 256, 256, 0, stream>>>(
        node_attrs, atomic_numbers, covalent_radii, node_data, out, n_nodes, n_elem);

    zbl_edge<<<(n_edges + 255) / 256, 256, 0, stream>>>(
        x, edge_index, node_data, out, n_edges);
}

// Round 2
// 275.851 us; speedup vs baseline: 1.1699x; 1.1699x over previous
//
#include <hip/hip_runtime.h>

#define KE_CONST 14.3996454784255f
#define CHUNK 16000          // nodes per LDS accumulator chunk (64,000 B < 64 KB static LDS cap)
#define EDGE_BLOCK 512       // 8 waves/block; 2 blocks/CU by LDS -> 16 waves/CU
#define TARGET_BLOCKS 512

// ---------------- node precompute: { Zf, Zf^0.3, covrad[Z], 0 } ----------------
__global__ void zbl_node_prep(const float* __restrict__ node_attrs,
                              const int* __restrict__ atomic_numbers,
                              const float* __restrict__ covalent_radii,
                              float4* __restrict__ node_data,
                              float* __restrict__ out_zero_or_null,
                              int n_nodes, int n_elem) {
    int n = blockIdx.x * blockDim.x + threadIdx.x;
    if (n >= n_nodes) return;
    const float* row = node_attrs + (size_t)n * n_elem;
    float best = row[0];
    int bi = 0;
    for (int i = 1; i < n_elem; ++i) {
        float v = row[i];
        if (v > best) { best = v; bi = i; }
    }
    int Z = atomic_numbers[bi];
    float zf = (float)Z;
    float zp = __powf(zf, 0.3f);
    float cr = covalent_radii[Z];
    node_data[n] = make_float4(zf, zp, cr, 0.0f);
    if (out_zero_or_null) out_zero_or_null[n] = 0.0f;
}

// ---------------- per-edge math ----------------
__device__ __forceinline__ float zbl_val(float xv, const float4& du, const float4& dv,
                                         float rmax) {
    const float inv_a_pref = 1.0f / (0.4543f * 0.529f);
    float t = xv * (du.y + dv.y) * inv_a_pref;
    float phi = 0.1818f  * __expf(-3.2f    * t)
              + 0.5099f  * __expf(-0.9423f * t)
              + 0.2802f  * __expf(-0.4028f * t)
              + 0.02817f * __expf(-0.2016f * t);
    float v = KE_CONST * du.x * dv.x * phi / xv;
    float rr = xv / rmax;
    float r2 = rr * rr;
    float r6 = r2 * r2 * r2;
    float env = 1.0f - 28.0f * r6 + 48.0f * r6 * rr - 21.0f * r6 * r2;
    return 0.5f * v * env;
}

// ---------------- fast path: chunked LDS accumulation, no global atomics ----------------
__global__ __launch_bounds__(EDGE_BLOCK, 1)
void zbl_edge_chunk(const float* __restrict__ x,
                    const int* __restrict__ ei,
                    const float4* __restrict__ nd,
                    float* __restrict__ partial,
                    int n_edges, int n_nodes, int C, int B) {
    int c = blockIdx.x / B;
    int b = blockIdx.x - c * B;
    int lo = (int)(((long long)c * n_nodes) / C);
    int hi = (int)(((long long)(c + 1) * n_nodes) / C);

    __shared__ __align__(16) float acc[CHUNK];
    for (int i = threadIdx.x * 4; i < CHUNK; i += EDGE_BLOCK * 4) {
        *(float4*)&acc[i] = make_float4(0.f, 0.f, 0.f, 0.f);
    }
    __syncthreads();

    const int* __restrict__ rcv = ei + n_edges;
    long long e0 = (((long long)b * n_edges) / B) & ~3LL;
    long long e1 = (b == B - 1) ? (long long)n_edges
                                : ((((long long)(b + 1) * n_edges) / B) & ~3LL);
    bool vec_ok = ((n_edges & 3) == 0);  // int4/float4 row-base alignment

    if (vec_ok) {
        for (long long base = e0 + (long long)threadIdx.x * 4; base < e1;
             base += (long long)EDGE_BLOCK * 4) {
            if (base + 4 <= e1) {
                int4 r4 = *(const int4*)(rcv + base);
                bool a0 = (r4.x >= lo) & (r4.x < hi);
                bool a1 = (r4.y >= lo) & (r4.y < hi);
                bool a2 = (r4.z >= lo) & (r4.z < hi);
                bool a3 = (r4.w >= lo) & (r4.w < hi);
                if (!(a0 | a1 | a2 | a3)) continue;
                int4 s4 = *(const int4*)(ei + base);
                float4 x4 = *(const float4*)(x + base);
                int   rr[4] = {r4.x, r4.y, r4.z, r4.w};
                int   ss[4] = {s4.x, s4.y, s4.z, s4.w};
                float xx[4] = {x4.x, x4.y, x4.z, x4.w};
                bool  aa[4] = {a0, a1, a2, a3};
                #pragma unroll
                for (int k = 0; k < 4; ++k) {
                    if (!aa[k]) continue;
                    float4 du = nd[ss[k]];
                    float4 dv = nd[rr[k]];
                    float rmax = du.z + dv.z;
                    float xv = xx[k];
                    if (xv >= rmax) continue;
                    atomicAdd(&acc[rr[k] - lo], zbl_val(xv, du, dv, rmax));
                }
            } else {
                for (long long e = base; e < e1; ++e) {
                    int r = rcv[e];
                    if (r < lo || r >= hi) continue;
                    float4 du = nd[ei[e]];
                    float4 dv = nd[r];
                    float rmax = du.z + dv.z;
                    float xv = x[e];
                    if (xv >= rmax) continue;
                    atomicAdd(&acc[r - lo], zbl_val(xv, du, dv, rmax));
                }
            }
        }
    } else {
        for (long long e = e0 + threadIdx.x; e < e1; e += EDGE_BLOCK) {
            int r = rcv[e];
            if (r < lo || r >= hi) continue;
            float4 du = nd[ei[e]];
            float4 dv = nd[r];
            float rmax = du.z + dv.z;
            float xv = x[e];
            if (xv >= rmax) continue;
            atomicAdd(&acc[r - lo], zbl_val(xv, du, dv, rmax));
        }
    }

    __syncthreads();
    float* pout = partial + (size_t)blockIdx.x * CHUNK;
    for (int i = threadIdx.x * 4; i < CHUNK; i += EDGE_BLOCK * 4) {
        float4 v = *(const float4*)&acc[i];
        *(float4*)(pout + i) = v;
    }
}

// ---------------- reduce partials -> out (fully overwrites out) ----------------
__global__ void zbl_reduce(const float* __restrict__ partial,
                           float* __restrict__ out,
                           int n_nodes, int C, int B) {
    int i = blockIdx.x * blockDim.x + threadIdx.x;
    if (i >= n_nodes) return;
    int c = (int)((((long long)i + 1) * C - 1) / n_nodes);
    int lo = (int)(((long long)c * n_nodes) / C);
    const float* p = partial + ((size_t)c * B) * CHUNK + (i - lo);
    float s0 = 0.f, s1 = 0.f, s2 = 0.f, s3 = 0.f;
    int b = 0;
    for (; b + 4 <= B; b += 4) {
        s0 += p[(size_t)(b + 0) * CHUNK];
        s1 += p[(size_t)(b + 1) * CHUNK];
        s2 += p[(size_t)(b + 2) * CHUNK];
        s3 += p[(size_t)(b + 3) * CHUNK];
    }
    for (; b < B; ++b) s0 += p[(size_t)b * CHUNK];
    out[i] = (s0 + s1) + (s2 + s3);
}

// ---------------- fallback: direct device atomics (round-1 behavior) ----------------
__global__ void zbl_edge_atomic(const float* __restrict__ x,
                                const int* __restrict__ edge_index,
                                const float4* __restrict__ node_data,
                                float* __restrict__ out,
                                int n_edges) {
    int e = blockIdx.x * blockDim.x + threadIdx.x;
    if (e >= n_edges) return;
    int snd = edge_index[e];
    int r = edge_index[n_edges + e];
    float xv = x[e];
    float4 du = node_data[snd];
    float4 dv = node_data[r];
    float rmax = du.z + dv.z;
    if (xv >= rmax) return;
    atomicAdd(&out[r], zbl_val(xv, du, dv, rmax));
}

extern "C" void kernel_launch(void* const* d_in, const int* in_sizes, int n_in,
                              void* d_out, int out_size, void* d_ws, size_t ws_size,
                              hipStream_t stream) {
    const float* x              = (const float*)d_in[0];
    const float* node_attrs     = (const float*)d_in[1];
    const int*   edge_index     = (const int*)d_in[2];
    const int*   atomic_numbers = (const int*)d_in[3];
    const float* covalent_radii = (const float*)d_in[4];
    float* out = (float*)d_out;

    int n_edges = in_sizes[0];
    int n_elem  = in_sizes[3];
    int n_nodes = in_sizes[1] / n_elem;

    int C = (n_nodes + CHUNK - 1) / CHUNK;
    if (C < 1) C = 1;
    int B = TARGET_BLOCKS / C;
    if (B < 1) B = 1;
    int G = C * B;

    size_t nd_bytes   = (((size_t)n_nodes * sizeof(float4)) + 255) & ~(size_t)255;
    size_t part_bytes = (size_t)G * CHUNK * sizeof(float);
    bool fast = (ws_size >= nd_bytes + part_bytes);

    float4* node_data = (float4*)d_ws;

    if (fast) {
        float* partial = (float*)((char*)d_ws + nd_bytes);
        zbl_node_prep<<<(n_nodes + 255) / 256, 256, 0, stream>>>(
            node_attrs, atomic_numbers, covalent_radii, node_data,
            nullptr, n_nodes, n_elem);
        zbl_edge_chunk<<<G, EDGE_BLOCK, 0, stream>>>(
            x, edge_index, node_data, partial, n_edges, n_nodes, C, B);
        zbl_reduce<<<(n_nodes + 255) / 256, 256, 0, stream>>>(
            partial, out, n_nodes, C, B);
    } else {
        zbl_node_prep<<<(n_nodes + 255) / 256, 256, 0, stream>>>(
            node_attrs, atomic_numbers, covalent_radii, node_data,
            out, n_nodes, n_elem);
        zbl_edge_atomic<<<(n_edges + 255) / 256, 256, 0, stream>>>(
            x, edge_index, node_data, out, n_edges);
    }
}

// Round 3
// 236.371 us; speedup vs baseline: 1.3653x; 1.1670x over previous
//
#include <hip/hip_runtime.h>

#define KE_CONST 14.3996454784255f

// power-of-2 chunking for the fast path
#define P2_SHIFT 14
#define P2_CHUNK 16384            // 64 KB LDS accumulator
#define NB_BIN   1024             // binning blocks
#define BLK_A    256
#define BLK_B    256
#define B2_ACC   40               // accumulator blocks per chunk
#define MAXC     16

// legacy fallback path params (round-2)
#define CHUNK 16000
#define EDGE_BLOCK 512
#define TARGET_BLOCKS 512

// ---------------- node precompute: { Zf, Zf^0.3, covrad[Z], 0 } ----------------
__global__ void zbl_node_prep(const float* __restrict__ node_attrs,
                              const int* __restrict__ atomic_numbers,
                              const float* __restrict__ covalent_radii,
                              float4* __restrict__ node_data,
                              float* __restrict__ out_zero_or_null,
                              int n_nodes, int n_elem) {
    int n = blockIdx.x * blockDim.x + threadIdx.x;
    if (n >= n_nodes) return;
    const float* row = node_attrs + (size_t)n * n_elem;
    float best = row[0];
    int bi = 0;
    for (int i = 1; i < n_elem; ++i) {
        float v = row[i];
        if (v > best) { best = v; bi = i; }
    }
    int Z = atomic_numbers[bi];
    float zf = (float)Z;
    float zp = __powf(zf, 0.3f);
    float cr = covalent_radii[Z];
    node_data[n] = make_float4(zf, zp, cr, 0.0f);
    if (out_zero_or_null) out_zero_or_null[n] = 0.0f;
}

// ---------------- per-edge math ----------------
__device__ __forceinline__ float zbl_val(float xv, const float4& du, const float4& dv,
                                         float rmax) {
    const float inv_a_pref = 1.0f / (0.4543f * 0.529f);
    float t = xv * (du.y + dv.y) * inv_a_pref;
    float phi = 0.1818f  * __expf(-3.2f    * t)
              + 0.5099f  * __expf(-0.9423f * t)
              + 0.2802f  * __expf(-0.4028f * t)
              + 0.02817f * __expf(-0.2016f * t);
    float v = KE_CONST * du.x * dv.x * phi / xv;
    float rr = xv / rmax;
    float r2 = rr * rr;
    float r6 = r2 * r2 * r2;
    float env = 1.0f - 28.0f * r6 + 48.0f * r6 * rr - 21.0f * r6 * r2;
    return 0.5f * v * env;
}

// ---------------- fast path pass 1: dense compute + wave-aggregated binning ----------------
// Each block owns a contiguous edge slice and C private segments (one per chunk).
// Surviving records {rcv & (P2_CHUNK-1), val} are appended via ballot-aggregated
// LDS counters. No global atomics. Per-block counts written to cnt[].
__global__ __launch_bounds__(BLK_A)
void zbl_bin(const float* __restrict__ x,
             const int* __restrict__ ei,
             const float4* __restrict__ nd,
             uint2* __restrict__ pairs,
             unsigned* __restrict__ cnt,
             int n_edges, int C, int SUBCAP, int NB) {
    int b0 = blockIdx.x;
    long long e0 = (long long)b0 * n_edges / NB;
    long long e1 = (long long)(b0 + 1) * n_edges / NB;

    __shared__ unsigned off[MAXC];
    if (threadIdx.x < (unsigned)C) off[threadIdx.x] = 0;
    __syncthreads();

    const int* __restrict__ rcv = ei + n_edges;
    int lane = threadIdx.x & 63;

    for (long long base = e0; base < e1; base += BLK_A) {
        long long e = base + threadIdx.x;
        bool valid = (e < e1);
        int r = valid ? rcv[e] : 0;
        int s = valid ? ei[e] : 0;
        float xv = valid ? x[e] : 1e30f;
        float4 du = nd[s];
        float4 dv = nd[r];
        float rmax = du.z + dv.z;
        bool keep = valid && (xv < rmax);
        float val = zbl_val(xv, du, dv, rmax);  // dense; unused when !keep
        int bkt = r >> P2_SHIFT;

        for (int b = 0; b < C; ++b) {
            unsigned long long m = __ballot(keep && (bkt == b));
            if (m == 0ULL) continue;
            int leader = __ffsll((long long)m) - 1;
            unsigned wbase = 0;
            if (lane == leader) wbase = atomicAdd(&off[b], (unsigned)__popcll(m));
            wbase = (unsigned)__shfl((int)wbase, leader, 64);
            if (keep && (bkt == b)) {
                unsigned rank = wbase + (unsigned)__popcll(m & ((1ULL << lane) - 1ULL));
                if (rank < (unsigned)SUBCAP) {
                    pairs[((size_t)b0 * C + b) * SUBCAP + rank] =
                        make_uint2((unsigned)(r & (P2_CHUNK - 1)), __float_as_uint(val));
                }
            }
        }
    }
    __syncthreads();
    if (threadIdx.x < (unsigned)C) {
        unsigned v = off[threadIdx.x];
        cnt[b0 * C + threadIdx.x] = v < (unsigned)SUBCAP ? v : (unsigned)SUBCAP;
    }
}

// ---------------- fast path pass 2: dense LDS accumulation of binned records ----------------
__global__ __launch_bounds__(BLK_B)
void zbl_accum(const uint2* __restrict__ pairs,
               const unsigned* __restrict__ cnt,
               float* __restrict__ partial,
               int C, int SUBCAP, int NB, int B2) {
    int c = blockIdx.x / B2;
    int j = blockIdx.x - c * B2;

    __shared__ __align__(16) float acc[P2_CHUNK];
    for (int i = threadIdx.x * 4; i < P2_CHUNK; i += BLK_B * 4)
        *(float4*)&acc[i] = make_float4(0.f, 0.f, 0.f, 0.f);
    __syncthreads();

    int s0 = j * NB / B2;
    int s1 = (j + 1) * NB / B2;
    for (int b0 = s0; b0 < s1; ++b0) {
        unsigned n = cnt[b0 * C + c];
        const uint2* __restrict__ seg = pairs + ((size_t)b0 * C + c) * SUBCAP;
        for (unsigned i = threadIdx.x; i < n; i += BLK_B) {
            uint2 rec = seg[i];
            atomicAdd(&acc[rec.x], __uint_as_float(rec.y));
        }
    }
    __syncthreads();

    float* p = partial + ((size_t)c * B2 + j) * P2_CHUNK;
    for (int i = threadIdx.x * 4; i < P2_CHUNK; i += BLK_B * 4)
        *(float4*)(p + i) = *(const float4*)&acc[i];
}

// ---------------- fast path pass 3: reduce partials, overwrite out ----------------
__global__ void zbl_reduce_p2(const float* __restrict__ partial,
                              float* __restrict__ out,
                              int n_nodes, int B2) {
    int i = blockIdx.x * blockDim.x + threadIdx.x;
    if (i >= n_nodes) return;
    int c = i >> P2_SHIFT;
    int li = i & (P2_CHUNK - 1);
    const float* p = partial + ((size_t)c * B2) * P2_CHUNK + li;
    float s0 = 0.f, s1 = 0.f, s2 = 0.f, s3 = 0.f;
    int j = 0;
    for (; j + 4 <= B2; j += 4) {
        s0 += p[(size_t)(j + 0) * P2_CHUNK];
        s1 += p[(size_t)(j + 1) * P2_CHUNK];
        s2 += p[(size_t)(j + 2) * P2_CHUNK];
        s3 += p[(size_t)(j + 3) * P2_CHUNK];
    }
    for (; j < B2; ++j) s0 += p[(size_t)j * P2_CHUNK];
    out[i] = (s0 + s1) + (s2 + s3);
}

// ================= fallback path (round-2): chunked LDS with redundant scans =================
__global__ __launch_bounds__(EDGE_BLOCK, 1)
void zbl_edge_chunk(const float* __restrict__ x,
                    const int* __restrict__ ei,
                    const float4* __restrict__ nd,
                    float* __restrict__ partial,
                    int n_edges, int n_nodes, int C, int B) {
    int c = blockIdx.x / B;
    int b = blockIdx.x - c * B;
    int lo = (int)(((long long)c * n_nodes) / C);
    int hi = (int)(((long long)(c + 1) * n_nodes) / C);

    __shared__ __align__(16) float acc[CHUNK];
    for (int i = threadIdx.x * 4; i < CHUNK; i += EDGE_BLOCK * 4)
        *(float4*)&acc[i] = make_float4(0.f, 0.f, 0.f, 0.f);
    __syncthreads();

    const int* __restrict__ rcv = ei + n_edges;
    long long e0 = (((long long)b * n_edges) / B);
    long long e1 = (b == B - 1) ? (long long)n_edges : (((long long)(b + 1) * n_edges) / B);

    for (long long e = e0 + threadIdx.x; e < e1; e += EDGE_BLOCK) {
        int r = rcv[e];
        if (r < lo || r >= hi) continue;
        float4 du = nd[ei[e]];
        float4 dv = nd[r];
        float rmax = du.z + dv.z;
        float xv = x[e];
        if (xv >= rmax) continue;
        atomicAdd(&acc[r - lo], zbl_val(xv, du, dv, rmax));
    }

    __syncthreads();
    float* pout = partial + (size_t)blockIdx.x * CHUNK;
    for (int i = threadIdx.x * 4; i < CHUNK; i += EDGE_BLOCK * 4)
        *(float4*)(pout + i) = *(const float4*)&acc[i];
}

__global__ void zbl_reduce_old(const float* __restrict__ partial,
                               float* __restrict__ out,
                               int n_nodes, int C, int B) {
    int i = blockIdx.x * blockDim.x + threadIdx.x;
    if (i >= n_nodes) return;
    int c = (int)((((long long)i + 1) * C - 1) / n_nodes);
    int lo = (int)(((long long)c * n_nodes) / C);
    const float* p = partial + ((size_t)c * B) * CHUNK + (i - lo);
    float s = 0.f;
    for (int b = 0; b < B; ++b) s += p[(size_t)b * CHUNK];
    out[i] = s;
}

__global__ void zbl_edge_atomic(const float* __restrict__ x,
                                const int* __restrict__ edge_index,
                                const float4* __restrict__ node_data,
                                float* __restrict__ out,
                                int n_edges) {
    int e = blockIdx.x * blockDim.x + threadIdx.x;
    if (e >= n_edges) return;
    int snd = edge_index[e];
    int r = edge_index[n_edges + e];
    float xv = x[e];
    float4 du = node_data[snd];
    float4 dv = node_data[r];
    float rmax = du.z + dv.z;
    if (xv >= rmax) return;
    atomicAdd(&out[r], zbl_val(xv, du, dv, rmax));
}

extern "C" void kernel_launch(void* const* d_in, const int* in_sizes, int n_in,
                              void* d_out, int out_size, void* d_ws, size_t ws_size,
                              hipStream_t stream) {
    const float* x              = (const float*)d_in[0];
    const float* node_attrs     = (const float*)d_in[1];
    const int*   edge_index     = (const int*)d_in[2];
    const int*   atomic_numbers = (const int*)d_in[3];
    const float* covalent_radii = (const float*)d_in[4];
    float* out = (float*)d_out;

    int n_edges = in_sizes[0];
    int n_elem  = in_sizes[3];
    int n_nodes = in_sizes[1] / n_elem;

    float4* node_data = (float4*)d_ws;
    size_t nd_bytes = (((size_t)n_nodes * sizeof(float4)) + 255) & ~(size_t)255;

    // ---- fast path sizing ----
    int C = (n_nodes + P2_CHUNK - 1) >> P2_SHIFT;
    int NB = NB_BIN;
    int epb = (n_edges + NB - 1) / NB;
    int SUBCAP = epb / C + epb / (5 * C) + 128;   // mean + 20% + slack (>>10 sigma)
    size_t cnt_bytes   = ((size_t)NB * C * sizeof(unsigned) + 255) & ~(size_t)255;
    size_t pairs_bytes = ((size_t)NB * C * SUBCAP * sizeof(uint2) + 255) & ~(size_t)255;
    size_t part_bytes  = (size_t)C * B2_ACC * P2_CHUNK * sizeof(float);
    bool fast = (C >= 1) && (C <= MAXC) &&
                (ws_size >= nd_bytes + cnt_bytes + pairs_bytes + part_bytes);

    if (fast) {
        unsigned* cnt   = (unsigned*)((char*)d_ws + nd_bytes);
        uint2*    pairs = (uint2*)((char*)d_ws + nd_bytes + cnt_bytes);
        float*    part  = (float*)((char*)d_ws + nd_bytes + cnt_bytes + pairs_bytes);

        zbl_node_prep<<<(n_nodes + 255) / 256, 256, 0, stream>>>(
            node_attrs, atomic_numbers, covalent_radii, node_data,
            nullptr, n_nodes, n_elem);
        zbl_bin<<<NB, BLK_A, 0, stream>>>(
            x, edge_index, node_data, pairs, cnt, n_edges, C, SUBCAP, NB);
        zbl_accum<<<C * B2_ACC, BLK_B, 0, stream>>>(
            pairs, cnt, part, C, SUBCAP, NB, B2_ACC);
        zbl_reduce_p2<<<(n_nodes + 255) / 256, 256, 0, stream>>>(
            part, out, n_nodes, B2_ACC);
        return;
    }

    // ---- fallback: round-2 chunked path ----
    int Cf = (n_nodes + CHUNK - 1) / CHUNK;
    if (Cf < 1) Cf = 1;
    int Bf = TARGET_BLOCKS / Cf;
    if (Bf < 1) Bf = 1;
    int Gf = Cf * Bf;
    size_t partf_bytes = (size_t)Gf * CHUNK * sizeof(float);
    if (ws_size >= nd_bytes + partf_bytes) {
        float* partial = (float*)((char*)d_ws + nd_bytes);
        zbl_node_prep<<<(n_nodes + 255) / 256, 256, 0, stream>>>(
            node_attrs, atomic_numbers, covalent_radii, node_data,
            nullptr, n_nodes, n_elem);
        zbl_edge_chunk<<<Gf, EDGE_BLOCK, 0, stream>>>(
            x, edge_index, node_data, partial, n_edges, n_nodes, Cf, Bf);
        zbl_reduce_old<<<(n_nodes + 255) / 256, 256, 0, stream>>>(
            partial, out, n_nodes, Cf, Bf);
    } else {
        zbl_node_prep<<<(n_nodes + 255) / 256, 256, 0, stream>>>(
            node_attrs, atomic_numbers, covalent_radii, node_data,
            out, n_nodes, n_elem);
        zbl_edge_atomic<<<(n_edges + 255) / 256, 256, 0, stream>>>(
            x, edge_index, node_data, out, n_edges);
    }
}